// Round 7
// baseline (210.068 us; speedup 1.0000x reference)
//
#include <hip/hip_runtime.h>

#define BATCH  2048
#define NFEAT  256
#define DTOK   512
#define EPS    1e-5f
#define BCHUNK 32   // batches per wave (2 scalar-prefetch groups of 16)

typedef float fx4 __attribute__((ext_vector_type(4)));

// One wave (64 lanes) per feature f, looping over BCHUNK batches.
// W0/W1/bias/gamma/beta fragments live in registers. Row statistics come from
// 9 per-feature moments reduced ONCE per wave -> per-row loop has zero
// cross-lane ops. (v,m) wave-uniform -> SGPR prefetch (two groups of 16).
// Nontemporal stores (R6 A/B: nt 199.3 vs plain 202.4 -> keep nt).
// BCHUNK 16->32: halves per-row share of the ~1000-cycle wave prologue.
__global__ __launch_bounds__(256) void FeatureTokenizer_kernel(
    const float* __restrict__ values,
    const float* __restrict__ masks,
    const float* __restrict__ W,       // (F, 2, D)
    const float* __restrict__ bias,    // (F, D)
    const float* __restrict__ gamma,   // (D,)
    const float* __restrict__ beta,    // (D,)
    float* __restrict__ out)           // (B, F, D)
{
    const int lane = threadIdx.x & 63;
    const int wv   = threadIdx.x >> 6;
    const int bid  = blockIdx.x;        // 4096 blocks
    const int fg   = bid & 63;          // feature group (4 features each)
    const int bc   = bid >> 6;          // batch chunk (32 batches each)
    const int f    = fg * 4 + wv;
    const int b0   = bc * BCHUNK;

    const int dA = lane * 4;            // first 1KB half
    const int dB = dA + 256;            // second 1KB half

    const float* w0base = W + ((size_t)f * 2 + 0) * DTOK;
    const float* w1base = W + ((size_t)f * 2 + 1) * DTOK;
    const float* bbase  = bias + (size_t)f * DTOK;

    const fx4 w0a = *(const fx4*)(w0base + dA);
    const fx4 w0b = *(const fx4*)(w0base + dB);
    const fx4 w1a = *(const fx4*)(w1base + dA);
    const fx4 w1b = *(const fx4*)(w1base + dB);
    const fx4 ba  = *(const fx4*)(bbase  + dA);
    const fx4 bb  = *(const fx4*)(bbase  + dB);
    const fx4 ga  = *(const fx4*)(gamma + dA);
    const fx4 gb  = *(const fx4*)(gamma + dB);
    const fx4 ea  = *(const fx4*)(beta  + dA);
    const fx4 eb  = *(const fx4*)(beta  + dB);

    // per-lane partial moments over this lane's 8 elements
    float a0 = 0, a1 = 0, a2 = 0;
    float b00 = 0, b11 = 0, b22 = 0, b01 = 0, b02 = 0, b12 = 0;
#pragma unroll
    for (int j = 0; j < 4; ++j) {
        const float u0 = w0a[j], u1 = w1a[j], ub = ba[j];
        const float x0 = w0b[j], x1 = w1b[j], xb = bb[j];
        a0 += u0 + x0;  a1 += u1 + x1;  a2 += ub + xb;
        b00 = fmaf(u0, u0, fmaf(x0, x0, b00));
        b11 = fmaf(u1, u1, fmaf(x1, x1, b11));
        b22 = fmaf(ub, ub, fmaf(xb, xb, b22));
        b01 = fmaf(u0, u1, fmaf(x0, x1, b01));
        b02 = fmaf(u0, ub, fmaf(x0, xb, b02));
        b12 = fmaf(u1, ub, fmaf(x1, xb, b12));
    }

    // one-time wave-wide butterfly reduce of the 9 moments
#pragma unroll
    for (int off = 1; off < 64; off <<= 1) {
        a0  += __shfl_xor(a0,  off, 64);
        a1  += __shfl_xor(a1,  off, 64);
        a2  += __shfl_xor(a2,  off, 64);
        b00 += __shfl_xor(b00, off, 64);
        b11 += __shfl_xor(b11, off, 64);
        b22 += __shfl_xor(b22, off, 64);
        b01 += __shfl_xor(b01, off, 64);
        b02 += __shfl_xor(b02, off, 64);
        b12 += __shfl_xor(b12, off, 64);
    }

    for (int g = 0; g < BCHUNK / 16; ++g) {
        const int gb0 = b0 + g * 16;

        // prefetch wave-uniform (v, m) pairs (compiler -> scalar loads)
        float vs[16], ms[16];
#pragma unroll
        for (int i = 0; i < 16; ++i) {
            vs[i] = values[(size_t)(gb0 + i) * NFEAT + f];
            ms[i] = masks [(size_t)(gb0 + i) * NFEAT + f];
        }

#pragma unroll 4
        for (int i = 0; i < 16; ++i) {
            const float v = vs[i], m = ms[i];

            const float S  = fmaf(v, a0, fmaf(m, a1, a2));
            const float mu = S * (1.0f / DTOK);
            const float E2 = fmaf(v * v, b00, fmaf(m * m, b11,
                             fmaf(2.0f * v * m, b01,
                             fmaf(2.0f * v, b02, fmaf(2.0f * m, b12, b22)))));
            const float var  = E2 * (1.0f / DTOK) - mu * mu;
            const float rstd = rsqrtf(var + EPS);

            fx4 oA, oB;
#pragma unroll
            for (int j = 0; j < 4; ++j) {
                const float tA = fmaf(v, w0a[j], fmaf(m, w1a[j], ba[j]));
                const float tB = fmaf(v, w0b[j], fmaf(m, w1b[j], bb[j]));
                oA[j] = fmaf((tA - mu) * rstd, ga[j], ea[j]);
                oB[j] = fmaf((tB - mu) * rstd, gb[j], eb[j]);
            }

            float* orow = out + ((size_t)(gb0 + i) * NFEAT + f) * DTOK;
            __builtin_nontemporal_store(oA, (fx4*)(orow + dA));
            __builtin_nontemporal_store(oB, (fx4*)(orow + dB));
        }
    }
}

extern "C" void kernel_launch(void* const* d_in, const int* in_sizes, int n_in,
                              void* d_out, int out_size, void* d_ws, size_t ws_size,
                              hipStream_t stream) {
    const float* values = (const float*)d_in[0];
    const float* masks  = (const float*)d_in[1];
    const float* W      = (const float*)d_in[2];
    const float* bias   = (const float*)d_in[3];
    const float* gamma  = (const float*)d_in[4];
    const float* beta   = (const float*)d_in[5];
    float* out = (float*)d_out;

    // 64 feature-groups x 64 batch-chunks
    const int blocks = 64 * (BATCH / BCHUNK);
    FeatureTokenizer_kernel<<<blocks, 256, 0, stream>>>(
        values, masks, W, bias, gamma, beta, out);
}

// Round 8
// 200.041 us; speedup vs baseline: 1.0501x; 1.0501x over previous
//
#include <hip/hip_runtime.h>

#define BATCH  2048
#define NFEAT  256
#define DTOK   512
#define EPS    1e-5f
#define BCHUNK 16   // batches per wave (R7: 32 regressed 210 vs 199 -> keep 16)

typedef float fx4 __attribute__((ext_vector_type(4)));

// One wave (64 lanes) per feature f, looping over BCHUNK batches.
// W0/W1/bias/gamma/beta fragments live in registers. Row statistics come from
// 9 per-feature moments reduced ONCE per wave -> per-row loop has zero
// cross-lane ops. (v,m) wave-uniform -> SGPR prefetch.
// Nontemporal stores (R6 A/B: nt 199.3 vs plain 202.4).
// This is the measured-best R5 configuration (199.3 us).
__global__ __launch_bounds__(256) void FeatureTokenizer_kernel(
    const float* __restrict__ values,
    const float* __restrict__ masks,
    const float* __restrict__ W,       // (F, 2, D)
    const float* __restrict__ bias,    // (F, D)
    const float* __restrict__ gamma,   // (D,)
    const float* __restrict__ beta,    // (D,)
    float* __restrict__ out)           // (B, F, D)
{
    const int lane = threadIdx.x & 63;
    const int wv   = threadIdx.x >> 6;
    const int bid  = blockIdx.x;        // 8192 blocks
    const int fg   = bid & 63;          // feature group (4 features each)
    const int bc   = bid >> 6;          // batch chunk (16 batches each)
    const int f    = fg * 4 + wv;
    const int b0   = bc * BCHUNK;

    const int dA = lane * 4;            // first 1KB half
    const int dB = dA + 256;            // second 1KB half

    const float* w0base = W + ((size_t)f * 2 + 0) * DTOK;
    const float* w1base = W + ((size_t)f * 2 + 1) * DTOK;
    const float* bbase  = bias + (size_t)f * DTOK;

    const fx4 w0a = *(const fx4*)(w0base + dA);
    const fx4 w0b = *(const fx4*)(w0base + dB);
    const fx4 w1a = *(const fx4*)(w1base + dA);
    const fx4 w1b = *(const fx4*)(w1base + dB);
    const fx4 ba  = *(const fx4*)(bbase  + dA);
    const fx4 bb  = *(const fx4*)(bbase  + dB);
    const fx4 ga  = *(const fx4*)(gamma + dA);
    const fx4 gb  = *(const fx4*)(gamma + dB);
    const fx4 ea  = *(const fx4*)(beta  + dA);
    const fx4 eb  = *(const fx4*)(beta  + dB);

    // per-lane partial moments over this lane's 8 elements
    float a0 = 0, a1 = 0, a2 = 0;
    float b00 = 0, b11 = 0, b22 = 0, b01 = 0, b02 = 0, b12 = 0;
#pragma unroll
    for (int j = 0; j < 4; ++j) {
        const float u0 = w0a[j], u1 = w1a[j], ub = ba[j];
        const float x0 = w0b[j], x1 = w1b[j], xb = bb[j];
        a0 += u0 + x0;  a1 += u1 + x1;  a2 += ub + xb;
        b00 = fmaf(u0, u0, fmaf(x0, x0, b00));
        b11 = fmaf(u1, u1, fmaf(x1, x1, b11));
        b22 = fmaf(ub, ub, fmaf(xb, xb, b22));
        b01 = fmaf(u0, u1, fmaf(x0, x1, b01));
        b02 = fmaf(u0, ub, fmaf(x0, xb, b02));
        b12 = fmaf(u1, ub, fmaf(x1, xb, b12));
    }

    // one-time wave-wide butterfly reduce of the 9 moments
#pragma unroll
    for (int off = 1; off < 64; off <<= 1) {
        a0  += __shfl_xor(a0,  off, 64);
        a1  += __shfl_xor(a1,  off, 64);
        a2  += __shfl_xor(a2,  off, 64);
        b00 += __shfl_xor(b00, off, 64);
        b11 += __shfl_xor(b11, off, 64);
        b22 += __shfl_xor(b22, off, 64);
        b01 += __shfl_xor(b01, off, 64);
        b02 += __shfl_xor(b02, off, 64);
        b12 += __shfl_xor(b12, off, 64);
    }

    // prefetch wave-uniform (v, m) pairs into SGPRs
    float vs[BCHUNK], ms[BCHUNK];
#pragma unroll
    for (int i = 0; i < BCHUNK; ++i) {
        vs[i] = values[(size_t)(b0 + i) * NFEAT + f];
        ms[i] = masks [(size_t)(b0 + i) * NFEAT + f];
    }

#pragma unroll 4
    for (int i = 0; i < BCHUNK; ++i) {
        const float v = vs[i], m = ms[i];

        const float S  = fmaf(v, a0, fmaf(m, a1, a2));
        const float mu = S * (1.0f / DTOK);
        const float E2 = fmaf(v * v, b00, fmaf(m * m, b11,
                         fmaf(2.0f * v * m, b01,
                         fmaf(2.0f * v, b02, fmaf(2.0f * m, b12, b22)))));
        const float var  = E2 * (1.0f / DTOK) - mu * mu;
        const float rstd = rsqrtf(var + EPS);

        fx4 oA, oB;
#pragma unroll
        for (int j = 0; j < 4; ++j) {
            const float tA = fmaf(v, w0a[j], fmaf(m, w1a[j], ba[j]));
            const float tB = fmaf(v, w0b[j], fmaf(m, w1b[j], bb[j]));
            oA[j] = fmaf((tA - mu) * rstd, ga[j], ea[j]);
            oB[j] = fmaf((tB - mu) * rstd, gb[j], eb[j]);
        }

        float* orow = out + ((size_t)(b0 + i) * NFEAT + f) * DTOK;
        __builtin_nontemporal_store(oA, (fx4*)(orow + dA));
        __builtin_nontemporal_store(oB, (fx4*)(orow + dB));
    }
}

extern "C" void kernel_launch(void* const* d_in, const int* in_sizes, int n_in,
                              void* d_out, int out_size, void* d_ws, size_t ws_size,
                              hipStream_t stream) {
    const float* values = (const float*)d_in[0];
    const float* masks  = (const float*)d_in[1];
    const float* W      = (const float*)d_in[2];
    const float* bias   = (const float*)d_in[3];
    const float* gamma  = (const float*)d_in[4];
    const float* beta   = (const float*)d_in[5];
    float* out = (float*)d_out;

    // 64 feature-groups x 128 batch-chunks
    const int blocks = 64 * (BATCH / BCHUNK);
    FeatureTokenizer_kernel<<<blocks, 256, 0, stream>>>(
        values, masks, W, bias, gamma, beta, out);
}